// Round 1
// baseline (410.555 us; speedup 1.0000x reference)
//
#include <hip/hip_runtime.h>
#include <stdint.h>

typedef short bf16x8 __attribute__((ext_vector_type(8)));
typedef float f32x4 __attribute__((ext_vector_type(4)));

#define HD 64
#define NH 16
#define SEQ 2048
#define BATCH 2
#define DM 1024
#define TOK (BATCH * SEQ)

__device__ __forceinline__ unsigned short f2bf(float f) {
    union { float f; unsigned u; } a; a.f = f;
    unsigned r = a.u + 0x7fffu + ((a.u >> 16) & 1u);
    return (unsigned short)(r >> 16);
}
__device__ __forceinline__ float bf2f(unsigned short u) {
    union { unsigned u; float f; } a; a.u = ((unsigned)u) << 16;
    return a.f;
}

// ---------------- fp32 -> bf16 elementwise convert ----------------
__global__ void k_cvt(const float* __restrict__ in, unsigned short* __restrict__ out, int n) {
    int i = (blockIdx.x * blockDim.x + threadIdx.x) * 4;
    if (i >= n) return;
    float4 v = *(const float4*)(in + i);
    union { ushort4 v; unsigned short s[4]; } o;
    o.s[0] = f2bf(v.x); o.s[1] = f2bf(v.y); o.s[2] = f2bf(v.z); o.s[3] = f2bf(v.w);
    *(ushort4*)(out + i) = o.v;
}

// ---------------- fp32 (KxN) -> bf16 transposed (NxK) ----------------
__global__ void k_transpose_cvt(const float* __restrict__ W, unsigned short* __restrict__ Wt,
                                int K, int N) {
    __shared__ float tile[32][33];
    int bx = blockIdx.x, by = blockIdx.y;
    int tx = threadIdx.x, ty = threadIdx.y;  // block (32,8)
    for (int r = 0; r < 4; ++r) {
        int k = by * 32 + ty + r * 8;
        int n = bx * 32 + tx;
        tile[ty + r * 8][tx] = W[(size_t)k * N + n];
    }
    __syncthreads();
    for (int r = 0; r < 4; ++r) {
        int n = bx * 32 + ty + r * 8;
        int k = by * 32 + tx;
        Wt[(size_t)n * K + k] = f2bf(tile[tx][ty + r * 8]);
    }
}

// ---------------- bf16 MFMA GEMM, 128x128 tile, B^T input ----------------
// A: MxK row-major bf16.  Bt: NxK row-major bf16 (i.e. B transposed).
// C/D layout (verified m89): col = lane&15, row = (lane>>4)*4 + reg.
// A/B frag (16x16x32): lane holds 8 contiguous K elems at k0=(lane>>4)*8, row/col = lane&15.
#define BKK 32
#define LDK 40  // padded LDS row (bf16 elems)

// epilogue mode 0: plain fp32 store to C (N=1024)
// epilogue mode 1: QKV scatter (N=3072)
template <int MODE>
__device__ __forceinline__ void gemm_core(const unsigned short* __restrict__ A,
                                          const unsigned short* __restrict__ Bt,
                                          int K, int N,
                                          float* __restrict__ C,
                                          unsigned short* __restrict__ qbuf,
                                          unsigned short* __restrict__ kbuf,
                                          unsigned short* __restrict__ vt) {
    __shared__ unsigned short As[128 * LDK];
    __shared__ unsigned short Bs[128 * LDK];
    int tid = threadIdx.x;
    int lane = tid & 63, wave = tid >> 6;
    int row0 = blockIdx.y * 128;
    int col0 = blockIdx.x * 128;
    int wm = (wave >> 1) * 64, wn = (wave & 1) * 64;
    int fr = lane & 15;
    int fo = (lane >> 4) * 8;

    f32x4 zero4 = {0.f, 0.f, 0.f, 0.f};
    f32x4 acc[4][4];
    for (int i = 0; i < 4; ++i)
        for (int j = 0; j < 4; ++j) acc[i][j] = zero4;

    for (int k0 = 0; k0 < K; k0 += BKK) {
        __syncthreads();
        for (int i = 0; i < 2; ++i) {
            int c = tid + i * 256;
            int r = c >> 2, c8 = (c & 3) * 8;
            *(bf16x8*)&As[r * LDK + c8] = *(const bf16x8*)(A + (size_t)(row0 + r) * K + k0 + c8);
            *(bf16x8*)&Bs[r * LDK + c8] = *(const bf16x8*)(Bt + (size_t)(col0 + r) * K + k0 + c8);
        }
        __syncthreads();
        bf16x8 af[4], bf[4];
        for (int i = 0; i < 4; ++i) af[i] = *(const bf16x8*)&As[(wm + i * 16 + fr) * LDK + fo];
        for (int j = 0; j < 4; ++j) bf[j] = *(const bf16x8*)&Bs[(wn + j * 16 + fr) * LDK + fo];
        for (int i = 0; i < 4; ++i)
            for (int j = 0; j < 4; ++j)
                acc[i][j] = __builtin_amdgcn_mfma_f32_16x16x32_bf16(af[i], bf[j], acc[i][j], 0, 0, 0);
    }

    int rq = (lane >> 4) * 4;
    int cq = lane & 15;
    for (int i = 0; i < 4; ++i)
        for (int j = 0; j < 4; ++j)
            for (int reg = 0; reg < 4; ++reg) {
                int row = row0 + wm + i * 16 + rq + reg;  // token index
                int col = col0 + wn + j * 16 + cq;        // output col
                float v = acc[i][j][reg];
                if (MODE == 0) {
                    C[(size_t)row * N + col] = v;
                } else {
                    int which = col >> 10;
                    int hc = col & 1023;
                    int h = hc >> 6, d = hc & 63;
                    int b = row >> 11, s = row & (SEQ - 1);
                    int bh = b * NH + h;
                    unsigned short bv = f2bf(v);
                    if (which == 0)      qbuf[((size_t)bh * SEQ + s) * HD + d] = bv;
                    else if (which == 1) kbuf[((size_t)bh * SEQ + s) * HD + d] = bv;
                    else                 vt[((size_t)bh * HD + d) * SEQ + s] = bv;
                }
            }
}

__global__ void __launch_bounds__(256) k_gemm_qkv(const unsigned short* __restrict__ A,
                                                  const unsigned short* __restrict__ Bt,
                                                  unsigned short* __restrict__ qbuf,
                                                  unsigned short* __restrict__ kbuf,
                                                  unsigned short* __restrict__ vt) {
    gemm_core<1>(A, Bt, DM, 3 * DM, nullptr, qbuf, kbuf, vt);
}

__global__ void __launch_bounds__(256) k_gemm_out(const unsigned short* __restrict__ A,
                                                  const unsigned short* __restrict__ Bt,
                                                  float* __restrict__ C) {
    gemm_core<0>(A, Bt, DM, DM, C, nullptr, nullptr, nullptr);
}

// ---------------- RoPE in place on Q and K ([B*H][S][64] bf16) ----------------
__global__ void k_rope(unsigned short* __restrict__ qbuf, unsigned short* __restrict__ kbuf,
                       const float* __restrict__ cosb, const float* __restrict__ sinb) {
    int t = blockIdx.x * 256 + threadIdx.x;  // 2^20 threads total
    int c = t & 7;                           // 8-elem chunk within head dim
    int row = (t >> 3) & 65535;              // bh*SEQ + s  (65536 rows per buffer)
    int which = t >> 19;
    unsigned short* p = (which ? kbuf : qbuf) + (size_t)row * HD + c * 8;
    int s = row & (SEQ - 1);
    const float* cs = cosb + s * 32 + c * 4;
    const float* sn = sinb + s * 32 + c * 4;
    bf16x8 v = *(const bf16x8*)p;
    bf16x8 o;
    for (int i = 0; i < 4; ++i) {
        float x1 = bf2f((unsigned short)v[2 * i]);
        float x2 = bf2f((unsigned short)v[2 * i + 1]);
        float cc = cs[i], ss = sn[i];
        o[2 * i]     = (short)f2bf(x1 * cc - x2 * ss);
        o[2 * i + 1] = (short)f2bf(x1 * ss + x2 * cc);
    }
    *(bf16x8*)p = o;
}

// ---------------- Flash attention (causal, online softmax) ----------------
// grid: (SEQ/64, B*NH); block 256 = 4 waves; each wave owns 16 queries.
// Q,K: [B*H][S][64] bf16 (roped).  Vt: [B*H][64][S] bf16.  O: [B][S][H*64] bf16.
__global__ void __launch_bounds__(256) k_attn(const unsigned short* __restrict__ qbuf,
                                              const unsigned short* __restrict__ kbuf,
                                              const unsigned short* __restrict__ vt,
                                              unsigned short* __restrict__ obuf) {
    __shared__ unsigned short plds[4][16 * 32];  // per-wave P tile (16 q x 32 k)
    int tid = threadIdx.x;
    int lane = tid & 63, wave = tid >> 6;
    int bh = blockIdx.y;
    int b = bh >> 4, h = bh & 15;
    int qb = blockIdx.x * 64;
    int fr = lane & 15, quad = lane >> 4;

    const unsigned short* Qb = qbuf + (size_t)bh * SEQ * HD;
    const unsigned short* Kb = kbuf + (size_t)bh * SEQ * HD;
    const unsigned short* Vb = vt + (size_t)bh * HD * SEQ;

    int qrow = qb + wave * 16 + fr;
    bf16x8 qf0 = *(const bf16x8*)(Qb + (size_t)qrow * HD + quad * 8);
    bf16x8 qf1 = *(const bf16x8*)(Qb + (size_t)qrow * HD + 32 + quad * 8);

    f32x4 zero4 = {0.f, 0.f, 0.f, 0.f};
    f32x4 o[4];
    for (int j = 0; j < 4; ++j) o[j] = zero4;
    float m[4], l[4];
    for (int r = 0; r < 4; ++r) { m[r] = -1e30f; l[r] = 0.f; }

    const float scale = 0.125f;  // 1/sqrt(64)
    int nk = (qb + 64) >> 5;     // 32-key tiles (uniform across block)

    for (int kt = 0; kt < nk; ++kt) {
        int kb = kt * 32;
        f32x4 sg[2];
        for (int g = 0; g < 2; ++g) {
            int key = kb + g * 16 + fr;
            bf16x8 kfa = *(const bf16x8*)(Kb + (size_t)key * HD + quad * 8);
            bf16x8 kfb = *(const bf16x8*)(Kb + (size_t)key * HD + 32 + quad * 8);
            f32x4 z = zero4;
            z = __builtin_amdgcn_mfma_f32_16x16x32_bf16(qf0, kfa, z, 0, 0, 0);
            z = __builtin_amdgcn_mfma_f32_16x16x32_bf16(qf1, kfb, z, 0, 0, 0);
            sg[g] = z;
        }
        // scale + causal mask + row stats (rows live at quad*4+reg; cols across 16 lanes)
        float alpha[4];
        for (int reg = 0; reg < 4; ++reg) {
            int qr = qb + wave * 16 + quad * 4 + reg;
            float v0 = sg[0][reg] * scale;
            float v1 = sg[1][reg] * scale;
            v0 = ((kb + fr) <= qr) ? v0 : -1e30f;
            v1 = ((kb + 16 + fr) <= qr) ? v1 : -1e30f;
            float mv = fmaxf(v0, v1);
            for (int off = 1; off < 16; off <<= 1)
                mv = fmaxf(mv, __shfl_xor(mv, off, 16));
            float mn = fmaxf(m[reg], mv);
            alpha[reg] = __expf(m[reg] - mn);
            m[reg] = mn;
            float p0 = __expf(v0 - mn);
            float p1 = __expf(v1 - mn);
            sg[0][reg] = p0;
            sg[1][reg] = p1;
            float s2 = p0 + p1;
            for (int off = 1; off < 16; off <<= 1)
                s2 += __shfl_xor(s2, off, 16);
            l[reg] = l[reg] * alpha[reg] + s2;
        }
        for (int j = 0; j < 4; ++j)
            for (int reg = 0; reg < 4; ++reg) o[j][reg] *= alpha[reg];

        // P: D-layout -> LDS -> A-layout (verified m120 pattern)
        __syncthreads();
        unsigned short* pl = &plds[wave][0];
        for (int g = 0; g < 2; ++g)
            for (int reg = 0; reg < 4; ++reg)
                pl[(quad * 4 + reg) * 32 + g * 16 + fr] = f2bf(sg[g][reg]);
        __syncthreads();
        bf16x8 pf = *(const bf16x8*)(pl + fr * 32 + quad * 8);

        for (int j = 0; j < 4; ++j) {
            int d = j * 16 + fr;
            bf16x8 vf = *(const bf16x8*)(Vb + (size_t)d * SEQ + kb + quad * 8);
            o[j] = __builtin_amdgcn_mfma_f32_16x16x32_bf16(pf, vf, o[j], 0, 0, 0);
        }
    }

    for (int j = 0; j < 4; ++j)
        for (int reg = 0; reg < 4; ++reg) {
            int s = qb + wave * 16 + quad * 4 + reg;
            int d = j * 16 + fr;
            float val = o[j][reg] / l[reg];
            obuf[((size_t)(b * SEQ + s)) * DM + h * HD + d] = f2bf(val);
        }
}

extern "C" void kernel_launch(void* const* d_in, const int* in_sizes, int n_in,
                              void* d_out, int out_size, void* d_ws, size_t ws_size,
                              hipStream_t stream) {
    const float* x    = (const float*)d_in[0];
    const float* rc   = (const float*)d_in[1];
    const float* rs   = (const float*)d_in[2];
    const float* wqkv = (const float*)d_in[3];
    const float* wout = (const float*)d_in[4];
    float* out = (float*)d_out;

    char* ws = (char*)d_ws;
    size_t off = 0;
    auto alloc = [&](size_t bytes) {
        char* p = ws + off;
        off += (bytes + 255) & ~(size_t)255;
        return p;
    };
    unsigned short* xb    = (unsigned short*)alloc((size_t)TOK * DM * 2);
    unsigned short* wqkvt = (unsigned short*)alloc((size_t)3 * DM * DM * 2);
    unsigned short* woutt = (unsigned short*)alloc((size_t)DM * DM * 2);
    unsigned short* qbuf  = (unsigned short*)alloc((size_t)BATCH * NH * SEQ * HD * 2);
    unsigned short* kbuf  = (unsigned short*)alloc((size_t)BATCH * NH * SEQ * HD * 2);
    unsigned short* vtb   = (unsigned short*)alloc((size_t)BATCH * NH * SEQ * HD * 2);
    unsigned short* obuf  = (unsigned short*)alloc((size_t)TOK * DM * 2);

    k_cvt<<<(TOK * DM / 4 + 255) / 256, 256, 0, stream>>>(x, xb, TOK * DM);
    dim3 tb(32, 8);
    k_transpose_cvt<<<dim3(3 * DM / 32, DM / 32), tb, 0, stream>>>(wqkv, wqkvt, DM, 3 * DM);
    k_transpose_cvt<<<dim3(DM / 32, DM / 32), tb, 0, stream>>>(wout, woutt, DM, DM);
    k_gemm_qkv<<<dim3(3 * DM / 128, TOK / 128), 256, 0, stream>>>(xb, wqkvt, qbuf, kbuf, vtb);
    k_rope<<<4096, 256, 0, stream>>>(qbuf, kbuf, rc, rs);
    k_attn<<<dim3(SEQ / 64, BATCH * NH), 256, 0, stream>>>(qbuf, kbuf, vtb, obuf);
    k_gemm_out<<<dim3(DM / 128, TOK / 128), 256, 0, stream>>>(obuf, woutt, out);
}

// Round 2
// 409.426 us; speedup vs baseline: 1.0028x; 1.0028x over previous
//
#include <hip/hip_runtime.h>
#include <stdint.h>

typedef short bf16x8 __attribute__((ext_vector_type(8)));
typedef float f32x4 __attribute__((ext_vector_type(4)));

#define HD 64
#define NH 16
#define SEQ 2048
#define BATCH 2
#define DM 1024
#define TOK (BATCH * SEQ)

__device__ __forceinline__ unsigned short f2bf(float f) {
    union { float f; unsigned u; } a; a.f = f;
    unsigned r = a.u + 0x7fffu + ((a.u >> 16) & 1u);
    return (unsigned short)(r >> 16);
}
__device__ __forceinline__ float bf2f(unsigned short u) {
    union { unsigned u; float f; } a; a.u = ((unsigned)u) << 16;
    return a.f;
}

__device__ __forceinline__ float fexp2(float x) {
#if __has_builtin(__builtin_amdgcn_exp2f)
    return __builtin_amdgcn_exp2f(x);
#else
    return exp2f(x);
#endif
}

// 16-lane DPP shuffle step for reductions (rows of 16 lanes = DPP row).
template <int CTRL>
__device__ __forceinline__ float dppf(float x) {
#if __has_builtin(__builtin_amdgcn_update_dpp)
    int i = __float_as_int(x);
    return __int_as_float(__builtin_amdgcn_update_dpp(i, i, CTRL, 0xF, 0xF, false));
#else
    constexpr int off = (CTRL == 0xB1) ? 1 : (CTRL == 0x4E) ? 2 : (CTRL == 0x141) ? 4 : 8;
    return __shfl_xor(x, off, 16);
#endif
}

// ---------------- fp32 -> bf16 elementwise convert ----------------
__global__ void k_cvt(const float* __restrict__ in, unsigned short* __restrict__ out, int n) {
    int i = (blockIdx.x * blockDim.x + threadIdx.x) * 4;
    if (i >= n) return;
    float4 v = *(const float4*)(in + i);
    union { ushort4 v; unsigned short s[4]; } o;
    o.s[0] = f2bf(v.x); o.s[1] = f2bf(v.y); o.s[2] = f2bf(v.z); o.s[3] = f2bf(v.w);
    *(ushort4*)(out + i) = o.v;
}

// ---------------- fp32 (KxN) -> bf16 transposed (NxK) ----------------
__global__ void k_transpose_cvt(const float* __restrict__ W, unsigned short* __restrict__ Wt,
                                int K, int N) {
    __shared__ float tile[32][33];
    int bx = blockIdx.x, by = blockIdx.y;
    int tx = threadIdx.x, ty = threadIdx.y;  // block (32,8)
    for (int r = 0; r < 4; ++r) {
        int k = by * 32 + ty + r * 8;
        int n = bx * 32 + tx;
        tile[ty + r * 8][tx] = W[(size_t)k * N + n];
    }
    __syncthreads();
    for (int r = 0; r < 4; ++r) {
        int n = bx * 32 + ty + r * 8;
        int k = by * 32 + tx;
        Wt[(size_t)n * K + k] = f2bf(tile[tx][ty + r * 8]);
    }
}

// ---------------- bf16 MFMA GEMM, 128x128 tile, B^T input ----------------
#define BKK 32
#define LDK 40  // padded LDS row (bf16 elems)

template <int MODE>
__device__ __forceinline__ void gemm_core(const unsigned short* __restrict__ A,
                                          const unsigned short* __restrict__ Bt,
                                          int K, int N,
                                          float* __restrict__ C,
                                          unsigned short* __restrict__ qbuf,
                                          unsigned short* __restrict__ kbuf,
                                          unsigned short* __restrict__ vt) {
    __shared__ unsigned short As[128 * LDK];
    __shared__ unsigned short Bs[128 * LDK];
    int tid = threadIdx.x;
    int lane = tid & 63, wave = tid >> 6;
    int row0 = blockIdx.y * 128;
    int col0 = blockIdx.x * 128;
    int wm = (wave >> 1) * 64, wn = (wave & 1) * 64;
    int fr = lane & 15;
    int fo = (lane >> 4) * 8;

    f32x4 zero4 = {0.f, 0.f, 0.f, 0.f};
    f32x4 acc[4][4];
    for (int i = 0; i < 4; ++i)
        for (int j = 0; j < 4; ++j) acc[i][j] = zero4;

    for (int k0 = 0; k0 < K; k0 += BKK) {
        __syncthreads();
        for (int i = 0; i < 2; ++i) {
            int c = tid + i * 256;
            int r = c >> 2, c8 = (c & 3) * 8;
            *(bf16x8*)&As[r * LDK + c8] = *(const bf16x8*)(A + (size_t)(row0 + r) * K + k0 + c8);
            *(bf16x8*)&Bs[r * LDK + c8] = *(const bf16x8*)(Bt + (size_t)(col0 + r) * K + k0 + c8);
        }
        __syncthreads();
        bf16x8 af[4], bf[4];
        for (int i = 0; i < 4; ++i) af[i] = *(const bf16x8*)&As[(wm + i * 16 + fr) * LDK + fo];
        for (int j = 0; j < 4; ++j) bf[j] = *(const bf16x8*)&Bs[(wn + j * 16 + fr) * LDK + fo];
        for (int i = 0; i < 4; ++i)
            for (int j = 0; j < 4; ++j)
                acc[i][j] = __builtin_amdgcn_mfma_f32_16x16x32_bf16(af[i], bf[j], acc[i][j], 0, 0, 0);
    }

    int rq = (lane >> 4) * 4;
    int cq = lane & 15;
    for (int i = 0; i < 4; ++i)
        for (int j = 0; j < 4; ++j)
            for (int reg = 0; reg < 4; ++reg) {
                int row = row0 + wm + i * 16 + rq + reg;  // token index
                int col = col0 + wn + j * 16 + cq;        // output col
                float v = acc[i][j][reg];
                if (MODE == 0) {
                    C[(size_t)row * N + col] = v;
                } else {
                    int which = col >> 10;
                    int hc = col & 1023;
                    int h = hc >> 6, d = hc & 63;
                    int b = row >> 11, s = row & (SEQ - 1);
                    int bh = b * NH + h;
                    unsigned short bv = f2bf(v);
                    if (which == 0)      qbuf[((size_t)bh * SEQ + s) * HD + d] = bv;
                    else if (which == 1) kbuf[((size_t)bh * SEQ + s) * HD + d] = bv;
                    else                 vt[((size_t)bh * HD + d) * SEQ + s] = bv;
                }
            }
}

__global__ void __launch_bounds__(256) k_gemm_qkv(const unsigned short* __restrict__ A,
                                                  const unsigned short* __restrict__ Bt,
                                                  unsigned short* __restrict__ qbuf,
                                                  unsigned short* __restrict__ kbuf,
                                                  unsigned short* __restrict__ vt) {
    gemm_core<1>(A, Bt, DM, 3 * DM, nullptr, qbuf, kbuf, vt);
}

__global__ void __launch_bounds__(256) k_gemm_out(const unsigned short* __restrict__ A,
                                                  const unsigned short* __restrict__ Bt,
                                                  float* __restrict__ C) {
    gemm_core<0>(A, Bt, DM, DM, C, nullptr, nullptr, nullptr);
}

// ---------------- RoPE in place on Q and K ----------------
// Q additionally pre-scaled by softmax_scale * log2(e) so attention scores
// come out of QK^T already in exp2 units (saves all scale muls in k_attn).
__global__ void k_rope(unsigned short* __restrict__ qbuf, unsigned short* __restrict__ kbuf,
                       const float* __restrict__ cosb, const float* __restrict__ sinb) {
    int t = blockIdx.x * 256 + threadIdx.x;
    int c = t & 7;
    int row = (t >> 3) & 65535;
    int which = t >> 19;
    unsigned short* p = (which ? kbuf : qbuf) + (size_t)row * HD + c * 8;
    float sc = which ? 1.0f : (0.125f * 1.44269504f);  // 1/sqrt(64) * log2(e)
    int s = row & (SEQ - 1);
    const float* cs = cosb + s * 32 + c * 4;
    const float* sn = sinb + s * 32 + c * 4;
    bf16x8 v = *(const bf16x8*)p;
    bf16x8 o;
    for (int i = 0; i < 4; ++i) {
        float x1 = bf2f((unsigned short)v[2 * i]);
        float x2 = bf2f((unsigned short)v[2 * i + 1]);
        float cc = cs[i], ss = sn[i];
        o[2 * i]     = (short)f2bf((x1 * cc - x2 * ss) * sc);
        o[2 * i + 1] = (short)f2bf((x1 * ss + x2 * cc) * sc);
    }
    *(bf16x8*)p = o;
}

// ---------------- Flash attention (causal, online softmax) ----------------
// grid: (SEQ/64, B*NH); block 256 = 4 waves; each wave owns 16 queries,
// runs a barrier-free K-loop over 64-key tiles with its own trip count.
// Q pre-scaled so scores are in exp2 units. P transposes via per-wave LDS.
#define PSTR 72  // LDS row stride (bf16 elems), 16B-aligned, quad-staggered banks

__global__ void __launch_bounds__(256, 4) k_attn(const unsigned short* __restrict__ qbuf,
                                                 const unsigned short* __restrict__ kbuf,
                                                 const unsigned short* __restrict__ vt,
                                                 unsigned short* __restrict__ obuf) {
    __shared__ unsigned short plds[4][16 * PSTR];
    int tid = threadIdx.x;
    int lane = tid & 63, wave = tid >> 6;
    int bh = blockIdx.y;
    int b = bh >> 4, h = bh & 15;
    int qt = (int)gridDim.x - 1 - (int)blockIdx.x;  // biggest-work tiles dispatch first
    int qb = qt * 64;
    int fr = lane & 15, quad = lane >> 4;
    int Qmin = qb + wave * 16;  // this wave's first query row

    const unsigned short* Qb = qbuf + (size_t)bh * SEQ * HD;
    const unsigned short* Kb = kbuf + (size_t)bh * SEQ * HD;
    const unsigned short* Vb = vt + (size_t)bh * HD * SEQ;

    int qrow = Qmin + fr;
    bf16x8 qf0 = *(const bf16x8*)(Qb + (size_t)qrow * HD + quad * 8);
    bf16x8 qf1 = *(const bf16x8*)(Qb + (size_t)qrow * HD + 32 + quad * 8);

    f32x4 zero4 = {0.f, 0.f, 0.f, 0.f};
    f32x4 o[4];
    for (int j = 0; j < 4; ++j) o[j] = zero4;
    float m[4], l[4];
    for (int r = 0; r < 4; ++r) { m[r] = -1e30f; l[r] = 0.f; }

    unsigned short* pl = &plds[wave][0];
    int nfull = (Qmin + 1) >> 6;  // tiles with kb+63 <= Qmin need no mask

    for (int kt = 0; kt <= nfull; ++kt) {
        int kb = kt * 64;
        // ---- K loads + QK^T (scores already in exp2 units) ----
        f32x4 sg[4];
        for (int g = 0; g < 4; ++g) {
            int key = kb + g * 16 + fr;
            bf16x8 ka = *(const bf16x8*)(Kb + (size_t)key * HD + quad * 8);
            bf16x8 kc = *(const bf16x8*)(Kb + (size_t)key * HD + 32 + quad * 8);
            f32x4 z = zero4;
            z = __builtin_amdgcn_mfma_f32_16x16x32_bf16(qf0, ka, z, 0, 0, 0);
            z = __builtin_amdgcn_mfma_f32_16x16x32_bf16(qf1, kc, z, 0, 0, 0);
            sg[g] = z;
        }
        // ---- V prefetch (latency hides under softmax) ----
        bf16x8 vf0[4], vf1[4];
        for (int j = 0; j < 4; ++j) {
            int d = j * 16 + fr;
            vf0[j] = *(const bf16x8*)(Vb + (size_t)d * SEQ + kb + quad * 8);
            vf1[j] = *(const bf16x8*)(Vb + (size_t)d * SEQ + kb + 32 + quad * 8);
        }
        // ---- causal mask: only the single diagonal tile ----
        if (kt == nfull) {
            for (int g = 0; g < 4; ++g)
                for (int reg = 0; reg < 4; ++reg) {
                    int qr = Qmin + quad * 4 + reg;
                    if (kb + g * 16 + fr > qr) sg[g][reg] = -1e30f;
                }
        }
        // ---- online softmax: DPP max-reduce, per-lane partial l ----
        float alpha[4];
        for (int reg = 0; reg < 4; ++reg) {
            float mv = fmaxf(fmaxf(sg[0][reg], sg[1][reg]), fmaxf(sg[2][reg], sg[3][reg]));
            mv = fmaxf(mv, dppf<0xB1>(mv));
            mv = fmaxf(mv, dppf<0x4E>(mv));
            mv = fmaxf(mv, dppf<0x141>(mv));
            mv = fmaxf(mv, dppf<0x140>(mv));
            float mn = fmaxf(m[reg], mv);
            alpha[reg] = fexp2(m[reg] - mn);
            m[reg] = mn;
            float ps = 0.f;
            for (int g = 0; g < 4; ++g) {
                float p = fexp2(sg[g][reg] - mn);
                sg[g][reg] = p;
                ps += p;
            }
            l[reg] = l[reg] * alpha[reg] + ps;  // per-lane partial; reduced at end
        }
        for (int j = 0; j < 4; ++j)
            for (int reg = 0; reg < 4; ++reg) o[j][reg] *= alpha[reg];

        // ---- P: D-layout -> per-wave LDS -> A-layout (no block barrier) ----
        for (int g = 0; g < 4; ++g)
            for (int reg = 0; reg < 4; ++reg) {
                union { float f; unsigned u; } a; a.f = sg[g][reg];
                pl[(quad * 4 + reg) * PSTR + g * 16 + fr] = (unsigned short)(a.u >> 16);
            }
        bf16x8 pf0 = *(const bf16x8*)(pl + fr * PSTR + quad * 8);
        bf16x8 pf1 = *(const bf16x8*)(pl + fr * PSTR + 32 + quad * 8);

        for (int j = 0; j < 4; ++j) {
            o[j] = __builtin_amdgcn_mfma_f32_16x16x32_bf16(pf0, vf0[j], o[j], 0, 0, 0);
            o[j] = __builtin_amdgcn_mfma_f32_16x16x32_bf16(pf1, vf1[j], o[j], 0, 0, 0);
        }
    }

    // ---- deferred l reduction + output ----
    for (int reg = 0; reg < 4; ++reg) {
        float s = l[reg];
        s += dppf<0xB1>(s);
        s += dppf<0x4E>(s);
        s += dppf<0x141>(s);
        s += dppf<0x140>(s);
#if __has_builtin(__builtin_amdgcn_rcpf)
        l[reg] = __builtin_amdgcn_rcpf(s);
#else
        l[reg] = 1.0f / s;
#endif
    }
    for (int j = 0; j < 4; ++j)
        for (int reg = 0; reg < 4; ++reg) {
            int s = Qmin + quad * 4 + reg;
            int d = j * 16 + fr;
            obuf[((size_t)(b * SEQ + s)) * DM + h * HD + d] = f2bf(o[j][reg] * l[reg]);
        }
}

extern "C" void kernel_launch(void* const* d_in, const int* in_sizes, int n_in,
                              void* d_out, int out_size, void* d_ws, size_t ws_size,
                              hipStream_t stream) {
    const float* x    = (const float*)d_in[0];
    const float* rc   = (const float*)d_in[1];
    const float* rs   = (const float*)d_in[2];
    const float* wqkv = (const float*)d_in[3];
    const float* wout = (const float*)d_in[4];
    float* out = (float*)d_out;

    char* ws = (char*)d_ws;
    size_t off = 0;
    auto alloc = [&](size_t bytes) {
        char* p = ws + off;
        off += (bytes + 255) & ~(size_t)255;
        return p;
    };
    unsigned short* xb    = (unsigned short*)alloc((size_t)TOK * DM * 2);
    unsigned short* wqkvt = (unsigned short*)alloc((size_t)3 * DM * DM * 2);
    unsigned short* woutt = (unsigned short*)alloc((size_t)DM * DM * 2);
    unsigned short* qbuf  = (unsigned short*)alloc((size_t)BATCH * NH * SEQ * HD * 2);
    unsigned short* kbuf  = (unsigned short*)alloc((size_t)BATCH * NH * SEQ * HD * 2);
    unsigned short* vtb   = (unsigned short*)alloc((size_t)BATCH * NH * SEQ * HD * 2);
    unsigned short* obuf  = (unsigned short*)alloc((size_t)TOK * DM * 2);

    k_cvt<<<(TOK * DM / 4 + 255) / 256, 256, 0, stream>>>(x, xb, TOK * DM);
    dim3 tb(32, 8);
    k_transpose_cvt<<<dim3(3 * DM / 32, DM / 32), tb, 0, stream>>>(wqkv, wqkvt, DM, 3 * DM);
    k_transpose_cvt<<<dim3(DM / 32, DM / 32), tb, 0, stream>>>(wout, woutt, DM, DM);
    k_gemm_qkv<<<dim3(3 * DM / 128, TOK / 128), 256, 0, stream>>>(xb, wqkvt, qbuf, kbuf, vtb);
    k_rope<<<4096, 256, 0, stream>>>(qbuf, kbuf, rc, rs);
    k_attn<<<dim3(SEQ / 64, BATCH * NH), 256, 0, stream>>>(qbuf, kbuf, vtb, obuf);
    k_gemm_out<<<dim3(DM / 128, TOK / 128), 256, 0, stream>>>(obuf, woutt, out);
}